// Round 2
// baseline (185.025 us; speedup 1.0000x reference)
//
#include <hip/hip_runtime.h>
#include <math.h>

// L = 2*pi*log2(e): exp(-2*pi*r^2) == exp2(-L*r^2), folded into point prep.
#define LCONST 9.064720283654388f
#define NK 16384

__device__ __forceinline__ float fexp2(float x) {
    return __builtin_amdgcn_exp2f(x);
}

// Prefold all points:
//   PD[k]  = (2L*dx, 2L*dy, 2L*dz, -L*|d|^2)   for dom (16384)
//   PS[e*1024+n] = (px, py, pz, -L*|p|^2)       e=0 -> C, e=1..16 -> C1 batch e-1
// Zero the prod accumulator.
__global__ void __launch_bounds__(256) k_prep(const float* __restrict__ C1,
                                              const float* __restrict__ C,
                                              const float* __restrict__ dom,
                                              float4* __restrict__ PD,
                                              float4* __restrict__ PS,
                                              float* __restrict__ prod) {
    int t = blockIdx.x * 256 + threadIdx.x;  // 0..17407
    if (t < NK) {
        float x = dom[3*t], y = dom[3*t+1], z = dom[3*t+2];
        PD[t] = make_float4(2.0f*LCONST*x, 2.0f*LCONST*y, 2.0f*LCONST*z,
                            -LCONST * (x*x + y*y + z*z));
    }
    if (t < 1024) {
        float x = C[3*t], y = C[3*t+1], z = C[3*t+2];
        PS[t] = make_float4(x, y, z, -LCONST * (x*x + y*y + z*z));
    } else if (t < 17408) {
        int j = t - 1024;
        float x = C1[3*j], y = C1[3*j+1], z = C1[3*j+2];
        PS[t] = make_float4(x, y, z, -LCONST * (x*x + y*y + z*z));
    }
    if (t < 16) prod[t] = 0.0f;
}

// Fused theta kernel: grid (64 k-blocks, nchunk n-chunks, 17 entities).
// thread = grid point k; loads are block-uniform (scalar path).
// TH[(chunk*17+ent)*NK + k] = sum over the n-chunk of exp2(-L*|d_k - p_n|^2).
__global__ void __launch_bounds__(256) k_theta(const float4* __restrict__ PD,
                                               const float4* __restrict__ PS,
                                               float* __restrict__ TH, int npc) {
    int k = blockIdx.x * 256 + threadIdx.x;
    int ent = blockIdx.z;
    float4 d = PD[k];
    const float4* P = PS + (ent << 10) + blockIdx.y * npc;
    float a0 = 0.0f, a1 = 0.0f, a2 = 0.0f, a3 = 0.0f;
    #pragma unroll 2
    for (int n = 0; n < npc; n += 4) {
        float4 p0 = P[n], p1 = P[n+1], p2 = P[n+2], p3 = P[n+3];
        a0 += fexp2(fmaf(d.x, p0.x, fmaf(d.y, p0.y, fmaf(d.z, p0.z, d.w + p0.w))));
        a1 += fexp2(fmaf(d.x, p1.x, fmaf(d.y, p1.y, fmaf(d.z, p1.z, d.w + p1.w))));
        a2 += fexp2(fmaf(d.x, p2.x, fmaf(d.y, p2.y, fmaf(d.z, p2.z, d.w + p2.w))));
        a3 += fexp2(fmaf(d.x, p3.x, fmaf(d.y, p3.y, fmaf(d.z, p3.z, d.w + p3.w))));
    }
    TH[(blockIdx.y * 17 + ent) * NK + k] = (a0 + a1) + (a2 + a3);
}

// Reduce: per grid point k, theta_c * theta_b summed over k -> prod[b].
__global__ void __launch_bounds__(256) k_reduce(const float* __restrict__ TH,
                                                float* __restrict__ prod, int nchunk) {
    int k = blockIdx.x * 256 + threadIdx.x;
    int lane = threadIdx.x & 63;
    float sc = 0.0f;
    for (int c = 0; c < nchunk; ++c) sc += TH[(c * 17 + 0) * NK + k];
    #pragma unroll
    for (int b = 0; b < 16; ++b) {
        float sb = 0.0f;
        for (int c = 0; c < nchunk; ++c) sb += TH[(c * 17 + 1 + b) * NK + k];
        float v = sb * sc;
        for (int off = 32; off; off >>= 1) v += __shfl_down(v, off, 64);
        if (lane == 0) atomicAdd(prod + b, v);
    }
}

__global__ void k_final(const float* __restrict__ prod, float* __restrict__ out) {
    int t = threadIdx.x;
    if (t < 16) {
        const float scale = 4.76837158203125e-4f;  // 8 * (1000/16384) / 1024
        float dot = prod[t] * scale;
        dot = fminf(fmaxf(dot, 0.0f), 1.0f);
        out[t] = 1.0f - dot;
    }
}

extern "C" void kernel_launch(void* const* d_in, const int* in_sizes, int n_in,
                              void* d_out, int out_size, void* d_ws, size_t ws_size,
                              hipStream_t stream) {
    const float* C1  = (const float*)d_in[0];   // (16,1024,3)
    const float* C   = (const float*)d_in[1];   // (1024,3)
    const float* dom = (const float*)d_in[2];   // (16384,3)
    float* out = (float*)d_out;                 // (16,)

    char* ws = (char*)d_ws;
    float4* PD = (float4*)(ws + 0);         // 16384*16 = 262144
    float4* PS = (float4*)(ws + 262144);    // 17408*16 -> ends 540672
    float*  TH = (float*)(ws + 540672);     // nchunk*17*16384*4

    // 2 n-chunks for full occupancy if ws allows; else 1.
    size_t need2 = 540672 + (size_t)2 * 17 * NK * 4 + 64;
    int nchunk = (ws_size >= need2) ? 2 : 1;
    float* prod = (float*)(ws + 540672 + (size_t)nchunk * 17 * NK * 4);

    k_prep<<<68, 256, 0, stream>>>(C1, C, dom, PD, PS, prod);
    k_theta<<<dim3(64, nchunk, 17), 256, 0, stream>>>(PD, PS, TH, 1024 / nchunk);
    k_reduce<<<64, 256, 0, stream>>>(TH, prod, nchunk);
    k_final<<<1, 64, 0, stream>>>(prod, out);
}